// Round 3
// baseline (83.679 us; speedup 1.0000x reference)
//
#include <hip/hip_runtime.h>
#include <math.h>

// EM-routing class-capsule layer, MI355X (gfx950).
// R8 (2nd resubmit — broker timeout three rounds running, never measured).
// Occupancy experiment. One position per thread (grid 1024, block 256),
// __launch_bounds__(256,4) to force VGPR<=128 -> 4 blocks/CU (16 waves/CU,
// 4 waves/SIMD) vs R7's 2 blocks/CU. Theory: R7 is stall-bound (~8x above
// VALU issue floor); barrier/LDS-latency stalls can only be hidden by
// OTHER blocks (the R7 position-twin shares the same __syncthreads, so its
// ILP cannot cross barriers). Per-position arithmetic is byte-identical to
// the R7-verified math:
//   - bit-faithful E-step shift 18*(max_{c,ch} lp - ln10)
//   - identical EPS placements, v_rcp_f32 divides, DPP+shfl butterflies
//   - sigma via exact identity  S r1(v-mu)^2 = S r1 v^2 - mu^2*(2-s1)
// Partials packed as float2 (S rv, S rv*v). LDS ~29.4 KB/block.

#define CI 32
#define CO 32
#define CH 18
#define NPOS 1024
#define OUT_ACT (16 * 32)     // 512 activation floats, then pose

constexpr float EPSF = 1e-9f;
constexpr float LN10 = 2.302585092994046f;

__device__ __forceinline__ float fast_rcp(float x) {
    return __builtin_amdgcn_rcpf(x);
}

template <int CTRL>
__device__ __forceinline__ float dppf(float x) {
    union { float f; int i; } u; u.f = x;
    u.i = __builtin_amdgcn_update_dpp(u.i, u.i, CTRL, 0xF, 0xF, true);
    return u.f;
}

// sum/max over each 32-lane group (lanes 0-31 and 32-63 independently).
__device__ __forceinline__ float bf_sum32(float x) {
    x += dppf<0xB1>(x);    // quad_perm xor1
    x += dppf<0x4E>(x);    // quad_perm xor2
    x += dppf<0x141>(x);   // row_half_mirror == xor4
    x += dppf<0x140>(x);   // row_mirror == xor8
    x += __shfl_xor(x, 16);
    return x;
}
__device__ __forceinline__ float bf_max32(float x) {
    x = fmaxf(x, dppf<0xB1>(x));
    x = fmaxf(x, dppf<0x4E>(x));
    x = fmaxf(x, dppf<0x141>(x));
    x = fmaxf(x, dppf<0x140>(x));
    x = fmaxf(x, __shfl_xor(x, 16));
    return x;
}

__global__ __launch_bounds__(256, 4) void caps_em_kernel(
    const float* __restrict__ x,
    const float* __restrict__ w,
    const float* __restrict__ beta_v,
    const float* __restrict__ beta_a,
    const float* __restrict__ coord_add,
    float* __restrict__ out)
{
    const int n  = blockIdx.x;
    const int t  = threadIdx.x;
    const int c  = t & 31;
    const int ig = t >> 5;            // 0..7
    const int wv = t >> 6;            // wave 0..3

    __shared__ float  pose[CI][16];
    __shared__ float  act_in[CI];
    __shared__ float  rs_part[4][CO];        // per-wave rs partials
    __shared__ float2 part2[4][CO * 19];     // (Srv, Srv*v) per ch, 19-pad
    __shared__ float2 muq_s[CO * 19];        // {mu, 0.5/sigma}
    __shared__ float  base_s[CO * 19];       // -0.5*log(sigma)

    // ---- load pose + activation (coalesced) ----
    const float* xrow = x + n * (CI * 17);
    for (int e = t; e < CI * 17; e += 256) {
        int i = e / 17, k = e % 17;
        float val = xrow[e];
        if (k < 16) pose[i][k] = val;
        else        act_in[i]  = val;
    }
    const float cx = coord_add[(n & 63) * 2 + 0];
    const float cy = coord_add[(n & 63) * 2 + 1];
    __syncthreads();

    // ---- votes: pose(4x4) @ w(4x4) per (i, c); thread owns i = 4*ig+k ----
    float v[4][16];
    #pragma unroll
    for (int k = 0; k < 4; ++k) {
        int i = ig * 4 + k;
        float wr[16];
        const float4* wp4 = (const float4*)(w + ((i * CO + c) << 4));
        #pragma unroll
        for (int q = 0; q < 4; ++q) {
            float4 wf = wp4[q];
            wr[q*4+0] = wf.x; wr[q*4+1] = wf.y; wr[q*4+2] = wf.z; wr[q*4+3] = wf.w;
        }
        float pr[16];
        const float4* pp4 = (const float4*)pose[i];
        #pragma unroll
        for (int q = 0; q < 4; ++q) {
            float4 pf = pp4[q];
            pr[q*4+0] = pf.x; pr[q*4+1] = pf.y; pr[q*4+2] = pf.z; pr[q*4+3] = pf.w;
        }
        #pragma unroll
        for (int a = 0; a < 4; ++a) {
            #pragma unroll
            for (int d = 0; d < 4; ++d) {
                float s = pr[a*4+0] * wr[0*4+d];
                s += pr[a*4+1] * wr[1*4+d];
                s += pr[a*4+2] * wr[2*4+d];
                s += pr[a*4+3] * wr[3*4+d];
                v[k][a*4+d] = s;
            }
        }
    }

    float rr[4];
    float act_c = 0.0f;
    float r_sum;

    for (int it = 0; it < 3; ++it) {
        if (it > 0) {
            // ---- E-step (exact reference shift), ch-outer ----
            float S[4], mx[4];
            #pragma unroll
            for (int k = 0; k < 4; ++k) { S[k] = 0.0f; mx[k] = -3.0e38f; }
            #pragma unroll
            for (int ch = 0; ch < CH; ++ch) {
                float2 mq = muq_s[c * 19 + ch];
                float  bs = base_s[c * 19 + ch];
                #pragma unroll
                for (int k = 0; k < 4; ++k) {
                    float vv = (ch == 0) ? cx
                             : ((ch == 1) ? cy : v[k][ch - 2]);
                    float d  = vv - mq.x;
                    float lp = bs - d * d * mq.y;
                    S[k] += lp;
                    mx[k] = fmaxf(mx[k], lp);
                }
            }
            #pragma unroll
            for (int k = 0; k < 4; ++k) {
                float m = bf_max32(mx[k]);         // max over (c,ch) for i
                float shift = 18.0f * (m - LN10);
                float pe = __expf(S[k] - shift);
                float ap = pe * act_c;
                float A  = bf_sum32(ap);           // sum over c
                float invA = fast_rcp(A + EPSF);
                float re = ap * invA;
                float sk = A * invA;               // = sum_c re (reassoc)
                float an = act_in[ig * 4 + k];
                rr[k] = re * an * fast_rcp(an * sk + EPSF);
            }
        } else {
            #pragma unroll
            for (int k = 0; k < 4; ++k) {
                float an = act_in[ig * 4 + k];
                rr[k] = (1.0f / 32.0f) * an * fast_rcp(an + EPSF);
            }
        }

        // ---- combined partials: rs + (Srr*v, Srr*v^2) pairs, xor32-prereduced ----
        {
            float prr = rr[0] + rr[1] + rr[2] + rr[3];
            float prs = prr + __shfl_xor(prr, 32);
            rs_part[wv][c] = prs;                 // both halves: same value
            float2* pp = &part2[wv][c * 19];
            float s0 = cx * prr, s1 = cy * prr;
            s0 += __shfl_xor(s0, 32);
            s1 += __shfl_xor(s1, 32);
            pp[0] = make_float2(s0, cx * s0);     // Srr*cx^2 = cx*(Srr*cx)
            pp[1] = make_float2(s1, cy * s1);
            #pragma unroll
            for (int ch = 2; ch < CH; ++ch) {
                float s = 0.0f, s2 = 0.0f;
                #pragma unroll
                for (int k = 0; k < 4; ++k) {
                    float rv = rr[k] * v[k][ch - 2];
                    s  += rv;
                    s2 += rv * v[k][ch - 2];
                }
                s  += __shfl_xor(s, 32);
                s2 += __shfl_xor(s2, 32);
                pp[ch] = make_float2(s, s2);
            }
        }
        __syncthreads();

        // ---- distributed reduce: rs, mu, sigma -> {mu,q} + base ----
        {
            float rs = rs_part[0][c] + rs_part[1][c]
                     + rs_part[2][c] + rs_part[3][c];
            r_sum = rs;
            float rsinv = fast_rcp(rs + EPSF);
            float s1 = rs * rsinv;
            float c2 = 2.0f - s1;
            for (int ch = ig; ch < CH; ch += 8) {
                int j = c * 19 + ch;
                float2 a0 = part2[0][j], a1 = part2[1][j];
                float2 a2 = part2[2][j], a3 = part2[3][j];
                float mu_un = a0.x + a1.x + a2.x + a3.x;
                float v2_un = a0.y + a1.y + a2.y + a3.y;
                float mu  = mu_un * rsinv;
                float sig = fmaxf(v2_un * rsinv - mu * mu * c2, 0.0f) + EPSF;
                muq_s[j]  = make_float2(mu, 0.5f * fast_rcp(sig));
                base_s[j] = -0.5f * __logf(sig);
            }
        }
        __syncthreads();

        // ---- activation softmax over c (butterflies only) ----
        {
            float logit;
            if (it == 2) {
                float cost = 0.0f;
                #pragma unroll
                for (int ch = 0; ch < CH; ++ch)
                    cost += beta_v[c * CH + ch] - base_s[c * 19 + ch];
                logit = 0.03f * (beta_a[c] - cost * r_sum);  // lambda=0.03
            } else {
                logit = r_sum;
            }
            float mxl = bf_max32(logit);
            float ex  = __expf(logit - mxl);
            act_c = ex * fast_rcp(bf_sum32(ex));
        }
    }

    // ---- fused spatial mean via atomics ----
    const float inv64 = 1.0f / 64.0f;
    const int b = n >> 6;
    if (t < CO)
        atomicAdd(&out[b * CO + t], act_c * inv64);
    for (int e = t; e < CO * CH; e += 256) {
        int cc = e / CH, ch = e - cc * CH;
        atomicAdd(&out[OUT_ACT + b * (CO * CH) + e], muq_s[cc * 19 + ch].x * inv64);
    }
}

extern "C" void kernel_launch(void* const* d_in, const int* in_sizes, int n_in,
                              void* d_out, int out_size, void* d_ws, size_t ws_size,
                              hipStream_t stream) {
    const float* x         = (const float*)d_in[0];
    const float* w         = (const float*)d_in[1];
    const float* beta_v    = (const float*)d_in[2];
    const float* beta_a    = (const float*)d_in[3];
    const float* coord_add = (const float*)d_in[4];
    float* out = (float*)d_out;

    hipMemsetAsync(out, 0, (size_t)out_size * sizeof(float), stream);
    caps_em_kernel<<<dim3(NPOS), dim3(256), 0, stream>>>(
        x, w, beta_v, beta_a, coord_add, out);
}